// Round 1
// baseline (569.897 us; speedup 1.0000x reference)
//
#include <hip/hip_runtime.h>

// Problem constants (from reference)
#define C_IN  8
#define H     32
#define W     32
#define C_OUT 16
#define KH    3
#define KW    3
#define OH    32
#define OW    32
#define N_IN  (C_IN * H * W)     // 8192
#define N_OUT (C_OUT * OH * OW)  // 16384
#define MROWS (N_IN + 1)         // 8193
#define MCOLS (N_OUT + 1)        // 16385

// Kernel A: materialize M directly (no memset + scatter — pure streaming stores).
// One block per row. col = k*256 + t  =>  j = t & 31 is loop-invariant per thread,
// so kw / kwok are hoisted out of the k-loop. Per element: decode (c, i), test kh,
// LDS-load the weight, select, store.
__global__ __launch_bounds__(256) void build_M(const float* __restrict__ wts,
                                               const float* __restrict__ bias,
                                               float* __restrict__ M) {
    const int row = blockIdx.x;
    const int t   = threadIdx.x;

    __shared__ float ldsW[C_OUT * KH * KW]; // 144 floats: w[c][kh][kw] for this row's cin
    __shared__ float ldsB[C_OUT];

    const int cin = row >> 10;        // row / (H*W), ==8 for bias row (unused there)
    const int iy  = (row >> 5) & 31;
    const int ix  = row & 31;

    if (row < N_IN && t < C_OUT * KH * KW) {
        int c = t / 9;                // t = c*9 + r
        int r = t - c * 9;
        ldsW[t] = wts[c * 72 + cin * 9 + r];
    }
    if (t < C_OUT) ldsB[t] = bias[t];
    __syncthreads();

    float* __restrict__ Mrow = M + (size_t)row * MCOLS;

    if (row == N_IN) {
        // bias row: M[N_IN, col] = bias[col/1024] for col<N_OUT; M[N_IN, N_OUT] = 1
        for (int k = 0; k < 65; ++k) {
            int col = k * 256 + t;
            if (col < N_OUT)       Mrow[col] = ldsB[col >> 10];
            else if (col == N_OUT) Mrow[col] = 1.0f;
        }
        return;
    }

    const int  j    = t & 31;
    const int  kw   = ix + 1 - j;                 // loop-invariant per thread
    const bool kwok = (unsigned)kw < 3u;
    const int  kwc  = kwok ? kw : 0;              // clamped for safe LDS index

    #pragma unroll 8
    for (int k = 0; k < 64; ++k) {
        int  col = k * 256 + t;
        int  c   = col >> 10;
        int  i   = (col >> 5) & 31;
        int  kh  = iy + 1 - i;
        bool khok = (unsigned)kh < 3u;
        int  khc  = khok ? kh : 0;
        float v   = ldsW[c * 9 + khc * 3 + kwc];
        Mrow[col] = (khok & kwok) ? v : 0.0f;
    }
    if (t == 0) Mrow[N_OUT] = 0.0f;               // last (homogeneous) column
}

// Kernel B: interval bounds. lo += min(w*l, w*u); hi += max(w*l, w*u)  (+ bias).
// Identical term selection to reference's pos/neg split.
__global__ __launch_bounds__(256) void bounds_kernel(const float* __restrict__ l_in,
                                                     const float* __restrict__ u_in,
                                                     const float* __restrict__ wts,
                                                     const float* __restrict__ bias,
                                                     float* __restrict__ out) {
    int tid = blockIdx.x * 256 + threadIdx.x;
    if (tid >= N_OUT) return;
    int c = tid >> 10;
    int i = (tid >> 5) & 31;
    int j = tid & 31;

    float lo = bias[c];
    float hi = lo;

    #pragma unroll
    for (int cin = 0; cin < C_IN; ++cin) {
        #pragma unroll
        for (int kh = 0; kh < KH; ++kh) {
            int iy = i - 1 + kh;
            if ((unsigned)iy >= (unsigned)H) continue;
            #pragma unroll
            for (int kw = 0; kw < KW; ++kw) {
                int ix = j - 1 + kw;
                if ((unsigned)ix >= (unsigned)W) continue;
                float w = wts[c * 72 + cin * 9 + kh * 3 + kw];
                int   r = cin * 1024 + iy * 32 + ix;
                float a = w * l_in[r];
                float b = w * u_in[r];
                lo += fminf(a, b);
                hi += fmaxf(a, b);
            }
        }
    }
    out[tid]         = lo;
    out[N_OUT + tid] = hi;
}

extern "C" void kernel_launch(void* const* d_in, const int* in_sizes, int n_in,
                              void* d_out, int out_size, void* d_ws, size_t ws_size,
                              hipStream_t stream) {
    const float* lower = (const float*)d_in[0];
    const float* upper = (const float*)d_in[1];
    const float* wts   = (const float*)d_in[2];
    const float* bias  = (const float*)d_in[3];

    float* out = (float*)d_out;
    float* M   = out + 2 * N_OUT;   // lo(16384) | hi(16384) | M(8193*16385)

    hipLaunchKernelGGL(build_M, dim3(MROWS), dim3(256), 0, stream, wts, bias, M);
    hipLaunchKernelGGL(bounds_kernel, dim3((N_OUT + 255) / 256), dim3(256), 0, stream,
                       lower, upper, wts, bias, out);
}